// Round 1
// 1250.769 us; speedup vs baseline: 1.0794x; 1.0794x over previous
//
#include <hip/hip_runtime.h>
#include <math.h>

#define B_    4
#define T_    2048
#define D_    1024
#define H_    4
#define DK_   256
#define DV_   512
#define KDIM_ 1024
#define VDIM_ 2048
#define FFN_  4096
#define BT_   8192   // B_*T_

typedef unsigned short bf16;
typedef __attribute__((ext_vector_type(8))) short short8;   // MFMA A/B frag (8 bf16)
typedef __attribute__((ext_vector_type(4))) short short4v;  // 4 bf16
typedef __attribute__((ext_vector_type(4))) float f32x4;    // MFMA C/D frag

// ---------------- helpers ----------------

__device__ __forceinline__ float sigmoidf_(float x) { return 1.f / (1.f + expf(-x)); }
__device__ __forceinline__ float siluf_(float x)    { return x / (1.f + expf(-x)); }
__device__ __forceinline__ float geluf_(float x)    { return 0.5f * x * (1.f + erff(x * 0.70710678118654752f)); }

__device__ __forceinline__ float bf2f(bf16 u) {
  union { unsigned int i; float f; } c; c.i = (unsigned int)u << 16; return c.f;
}
__device__ __forceinline__ bf16 f2bf(float f) {
  union { unsigned int i; float f; } c; c.f = f;
  unsigned int r = c.i + 0x7fffu + ((c.i >> 16) & 1u);   // RNE
  return (bf16)(r >> 16);
}

// async global->LDS, 16B per lane
__device__ __forceinline__ void gload16(const bf16* g, bf16* l) {
  __builtin_amdgcn_global_load_lds((__attribute__((address_space(1))) const void*)g,
                                   (__attribute__((address_space(3))) void*)l, 16, 0, 0);
}

__device__ __forceinline__ void storeC(float* p, float v) { *p = v; }
__device__ __forceinline__ void storeC(bf16* p, float v)  { *p = f2bf(v); }

// load 8 bf16 from an 8B-aligned LDS address as two b64s
__device__ __forceinline__ short8 ld76(const bf16* p) {
  union { short8 v; short4v h[2]; } u;
  u.h[0] = *(const short4v*)p;
  u.h[1] = *(const short4v*)(p + 4);
  return u.v;
}
// pack f32x4 -> 4 bf16, 8B store
__device__ __forceinline__ void st4bf(bf16* p, f32x4 v) {
  short4v o;
  o[0] = (short)f2bf(v[0]); o[1] = (short)f2bf(v[1]);
  o[2] = (short)f2bf(v[2]); o[3] = (short)f2bf(v[3]);
  *(short4v*)p = o;
}

__device__ __forceinline__ float block_sum256(float v, float* red) {
#pragma unroll
  for (int off = 32; off; off >>= 1) v += __shfl_xor(v, off, 64);
  __syncthreads();
  if ((threadIdx.x & 63) == 0) red[threadIdx.x >> 6] = v;
  __syncthreads();
  return red[0] + red[1] + red[2] + red[3];
}

// ---------------- diagnostic sentinel (ws too small) ----------------

__global__ __launch_bounds__(256) void sentinel_kernel(float* out, int n) {
  int i = blockIdx.x * 256 + threadIdx.x;
  if (i < n) out[i] = 12345.0f;
}

// ---------------- LayerNorm -> bf16 ----------------

__global__ __launch_bounds__(256) void ln_kernel(const float* __restrict__ x,
                                                 const float* __restrict__ w,
                                                 const float* __restrict__ b,
                                                 bf16* __restrict__ y) {
  __shared__ float red[4];
  int row = blockIdx.x;
  const float* xr = x + (size_t)row * D_;
  float xv[4];
  float s = 0.f;
#pragma unroll
  for (int i = 0; i < 4; i++) { xv[i] = xr[threadIdx.x + 256 * i]; s += xv[i]; }
  float mean = block_sum256(s, red) * (1.f / D_);
  float s2 = 0.f;
#pragma unroll
  for (int i = 0; i < 4; i++) { float d = xv[i] - mean; s2 += d * d; }
  float var = block_sum256(s2, red) * (1.f / D_);
  float inv = rsqrtf(var + 1e-5f);
  bf16* yr = y + (size_t)row * D_;
#pragma unroll
  for (int i = 0; i < 4; i++) {
    int c = threadIdx.x + 256 * i;
    yr[c] = f2bf((xv[i] - mean) * inv * w[c] + b[c]);
  }
}

// ---------------- weight convert+transpose: fp32 [K][N] -> bf16 [N][K] ----------------

__global__ __launch_bounds__(256) void convT_kernel(const float* __restrict__ src,
                                                    bf16* __restrict__ dst,
                                                    int K, int N) {
  __shared__ float t[32][33];
  int n0 = blockIdx.x * 32, k0 = blockIdx.y * 32;
  int tx = threadIdx.x & 31, ty = threadIdx.x >> 5;
#pragma unroll
  for (int i = 0; i < 4; i++)
    t[ty + i * 8][tx] = src[(size_t)(k0 + ty + i * 8) * N + n0 + tx];
  __syncthreads();
#pragma unroll
  for (int i = 0; i < 4; i++)
    dst[(size_t)(n0 + ty + i * 8) * K + k0 + tx] = f2bf(t[tx][ty + i * 8]);
}

// ---------------- k transpose per head: k16 [b][t][h*DK+dk] -> kT [bh][dk][t] ----------------

__global__ __launch_bounds__(256) void kT_kernel(const bf16* __restrict__ k16,
                                                 bf16* __restrict__ kT) {
  __shared__ bf16 tile[32][34];
  int t0 = blockIdx.x * 32;
  int d0 = blockIdx.y * 32;
  int bh = blockIdx.z;
  int b = bh >> 2, h = bh & 3;
  int tx = threadIdx.x & 31, ty = threadIdx.x >> 5;
#pragma unroll
  for (int i = 0; i < 4; i++)
    tile[ty + 8 * i][tx] = k16[(size_t)(b * T_ + t0 + ty + 8 * i) * KDIM_ + h * DK_ + d0 + tx];
  __syncthreads();
#pragma unroll
  for (int i = 0; i < 4; i++)
    kT[((size_t)bh * DK_ + d0 + ty + 8 * i) * T_ + t0 + tx] = tile[tx][ty + 8 * i];
}

// ---------------- bf16 MFMA GEMM (unchanged) ----------------

template <typename TC>
__global__ __launch_bounds__(256) void gemm_mfma(const bf16* __restrict__ A,
                                                 const bf16* __restrict__ Bt,
                                                 const float* __restrict__ bias,
                                                 const float* __restrict__ res,
                                                 TC* __restrict__ C,
                                                 int N, int K, int flags) {
  __shared__ __align__(16) bf16 As[128 * 32];
  __shared__ __align__(16) bf16 Bs[128 * 32];
  int tid = threadIdx.x;
  int wave = tid >> 6, lane = tid & 63;
  int bm = blockIdx.y * 128, bn = blockIdx.x * 128;
  int wm = (wave >> 1) * 64, wn = (wave & 1) * 64;
  int lm = lane & 15;
  int quad = lane >> 4;

  f32x4 acc[4][4];
#pragma unroll
  for (int i = 0; i < 4; i++)
#pragma unroll
    for (int j = 0; j < 4; j++) acc[i][j] = (f32x4){0.f, 0.f, 0.f, 0.f};

  int srow = wave * 32 + (lane >> 2);
  int scol = (lane & 3) * 8;
  const bf16* ag = A  + (size_t)(bm + srow) * K + scol;
  const bf16* bg = Bt + (size_t)(bn + srow) * K + scol;
  bf16* al = As + wave * 32 * 32;
  bf16* bl = Bs + wave * 32 * 32;
  const size_t gstep = (size_t)16 * K;

  for (int k0 = 0; k0 < K; k0 += 32) {
    gload16(ag + k0,         al);
    gload16(ag + k0 + gstep, al + 16 * 32);
    gload16(bg + k0,         bl);
    gload16(bg + k0 + gstep, bl + 16 * 32);
    __syncthreads();

    short8 af[4], bf[4];
#pragma unroll
    for (int i = 0; i < 4; i++)
      af[i] = *(const short8*)&As[(wm + i * 16 + lm) * 32 + quad * 8];
#pragma unroll
    for (int j = 0; j < 4; j++)
      bf[j] = *(const short8*)&Bs[(wn + j * 16 + lm) * 32 + quad * 8];
#pragma unroll
    for (int i = 0; i < 4; i++)
#pragma unroll
      for (int j = 0; j < 4; j++)
        acc[i][j] = __builtin_amdgcn_mfma_f32_16x16x32_bf16(af[i], bf[j], acc[i][j], 0, 0, 0);
    __syncthreads();
  }

#pragma unroll
  for (int i = 0; i < 4; i++) {
    int row0 = bm + wm + i * 16 + quad * 4;
#pragma unroll
    for (int j = 0; j < 4; j++) {
      int col = bn + wn + j * 16 + lm;
      float badd = (flags & 1) ? bias[col] : 0.f;
#pragma unroll
      for (int r = 0; r < 4; r++) {
        float v = acc[i][j][r] + badd;
        if (flags & 2) v = geluf_(v);
        if (flags & 4) v += res[(size_t)(row0 + r) * N + col];
        storeC(&C[(size_t)(row0 + r) * N + col], v);
      }
    }
  }
}

// ---------------- fused Wa/Wb projections -> g, beta ----------------

__global__ __launch_bounds__(256) void ab_kernel(const bf16* __restrict__ normed,
                                                 const float* __restrict__ Wa,
                                                 const float* __restrict__ Wb,
                                                 const float* __restrict__ A_log,
                                                 const float* __restrict__ dt_bias,
                                                 float* __restrict__ g,
                                                 float* __restrict__ beta) {
  __shared__ float red[4];
  int row = blockIdx.x;
  const bf16* xr = normed + (size_t)row * D_;
  float aacc[4] = {}, bacc[4] = {};
#pragma unroll
  for (int i = 0; i < 4; i++) {
    int d = threadIdx.x + 256 * i;
    float xv = bf2f(xr[d]);
    float4 wa = *(const float4*)&Wa[d * 4];
    float4 wb = *(const float4*)&Wb[d * 4];
    aacc[0] += xv * wa.x; aacc[1] += xv * wa.y; aacc[2] += xv * wa.z; aacc[3] += xv * wa.w;
    bacc[0] += xv * wb.x; bacc[1] += xv * wb.y; bacc[2] += xv * wb.z; bacc[3] += xv * wb.w;
  }
  float sa[4], sb[4];
#pragma unroll
  for (int h = 0; h < 4; h++) {
    sa[h] = block_sum256(aacc[h], red);
    sb[h] = block_sum256(bacc[h], red);
  }
  if (threadIdx.x < 4) {
    int h = threadIdx.x;
    float xa = sa[h] + dt_bias[h];
    float sp = (xa > 20.f) ? xa : log1pf(expf(xa));
    g[row * 4 + h] = -expf(A_log[h]) * sp;
    beta[row * 4 + h] = sigmoidf_(sb[h]);
  }
}

// ---------------- causal conv(4) + SiLU (+ L2 norm for q/k) ----------------

__global__ __launch_bounds__(256) void conv_qk_kernel(const float* __restrict__ pre,
                                                      const float* __restrict__ convw,
                                                      bf16* __restrict__ out,
                                                      float scale) {
  __shared__ float red[4];
  int blk = blockIdx.x;
  int h = blk & 3;
  int bt = blk >> 2;
  int t = bt & (T_ - 1);
  int c = h * DK_ + threadIdx.x;
  float y = 0.f;
#pragma unroll
  for (int i = 0; i < 4; i++) {
    int tt = t + i - 3;
    if (tt >= 0) y += pre[(size_t)(bt + i - 3) * KDIM_ + c] * convw[c * 4 + i];
  }
  y = siluf_(y);
  float ss = block_sum256(y * y, red);
  y *= rsqrtf(ss + 1e-6f) * scale;
  out[(size_t)bt * KDIM_ + c] = f2bf(y);
}

__global__ __launch_bounds__(256) void conv_v_kernel(const float* __restrict__ pre,
                                                     const float* __restrict__ convw,
                                                     bf16* __restrict__ out) {
  int idx = blockIdx.x * 256 + threadIdx.x;
  int c = idx & (VDIM_ - 1);
  int bt = idx >> 11;
  int t = bt & (T_ - 1);
  float y = 0.f;
#pragma unroll
  for (int i = 0; i < 4; i++) {
    int tt = t + i - 3;
    if (tt >= 0) y += pre[(size_t)(bt + i - 3) * VDIM_ + c] * convw[c * 4 + i];
  }
  out[idx] = f2bf(siluf_(y));
}

// ---------------- delta rule phase 1 (parallel over bh x chunk) ----------------

#define SP 76

__global__ __launch_bounds__(256, 2) void delta_p1(const bf16* __restrict__ q,
                                                   const bf16* __restrict__ k,
                                                   const bf16* __restrict__ v,
                                                   const float* __restrict__ g,
                                                   const float* __restrict__ beta,
                                                   bf16* __restrict__ Pg,
                                                   bf16* __restrict__ Wg,
                                                   bf16* __restrict__ Yg,
                                                   float* __restrict__ gsc) {
  __shared__ bf16 Abf[64 * SP];
  __shared__ bf16 DTg[64 * SP];
  __shared__ float Ub[64 * 64];
  __shared__ float Gc[64], Lm[64], Bt[64];

  int blk = blockIdx.x;
  int c = blk & 31, bh = blk >> 5;
  int b = bh >> 2, h = bh & 3;
  int tid = threadIdx.x;
  int wave = tid >> 6, lane = tid & 63;
  int lm = lane & 15, quad = lane >> 4;
  int r0 = c * 64;

  const bf16* kb = k + (size_t)b * T_ * KDIM_ + h * DK_;
  const bf16* qb = q + (size_t)b * T_ * KDIM_ + h * DK_;
  const bf16* vb = v + (size_t)b * T_ * VDIM_ + h * DV_;
  const float* gbp = g    + (size_t)b * T_ * H_ + h;
  const float* bbp = beta + (size_t)b * T_ * H_ + h;
  size_t cb = (size_t)bh * 32 + c;
  bf16* PgC = Pg + cb * 4096;
  bf16* WgC = Wg + cb * 64 * 512;
  bf16* YgC = Yg + cb * 64 * 256;

  // (a) cumsum of g -> Gc, Lam, beta
  if (wave == 0) {
    float gv = gbp[(size_t)(r0 + lane) * H_];
    float bv = bbp[(size_t)(r0 + lane) * H_];
#pragma unroll
    for (int d = 1; d < 64; d <<= 1) {
      float nn = __shfl_up(gv, (unsigned)d, 64);
      if (lane >= d) gv += nn;
    }
    Gc[lane] = gv; Lm[lane] = expf(gv); Bt[lane] = bv;
    gsc[cb * 64 + lane] = gv;
  }
  __syncthreads();

  // (b,c) KK^T -> Abf, QK^T -> Pg
  {
    f32x4 akk[4], aqk[4];
#pragma unroll
    for (int j = 0; j < 4; j++) { akk[j] = (f32x4){0.f,0.f,0.f,0.f}; aqk[j] = (f32x4){0.f,0.f,0.f,0.f}; }
    const bf16* krow = kb + (size_t)(r0 + 16 * wave + lm) * KDIM_;
    const bf16* qrow = qb + (size_t)(r0 + 16 * wave + lm) * KDIM_;
#pragma unroll
    for (int ks = 0; ks < 8; ks++) {
      short8 ak = *(const short8*)(krow + 8 * quad + 32 * ks);
      short8 aq = *(const short8*)(qrow + 8 * quad + 32 * ks);
#pragma unroll
      for (int j = 0; j < 4; j++) {
        short8 bk = *(const short8*)(kb + (size_t)(r0 + 16 * j + lm) * KDIM_ + 8 * quad + 32 * ks);
        akk[j] = __builtin_amdgcn_mfma_f32_16x16x32_bf16(ak, bk, akk[j], 0, 0, 0);
        aqk[j] = __builtin_amdgcn_mfma_f32_16x16x32_bf16(aq, bk, aqk[j], 0, 0, 0);
      }
    }
    float gi[4], bi[4];
#pragma unroll
    for (int r = 0; r < 4; r++) {
      int i = 16 * wave + 4 * quad + r;
      gi[r] = Gc[i]; bi[r] = Bt[i];
    }
#pragma unroll
    for (int j = 0; j < 4; j++) {
      int s = 16 * j + lm;
      float gs = Gc[s];
#pragma unroll
      for (int r = 0; r < 4; r++) {
        int i = 16 * wave + 4 * quad + r;
        float dec = expf(gi[r] - gs);
        Abf[(size_t)i * SP + s] = f2bf((s < i)  ? bi[r] * dec * akk[j][r] : 0.f);
        PgC[(size_t)i * 64 + s] = f2bf((s <= i) ? dec * aqk[j][r]        : 0.f);
      }
    }
  }

  // 12 column groups of 64: grp 0..7 -> W (RHS beta*V), grp 8..11 -> Y (RHS beta*Lam*K)
  for (int grp = 0; grp < 12; grp++) {
    __syncthreads();        // Abf ready (grp0) / prev DTg stores done
    {
      int* dz = (int*)DTg;
#pragma unroll
      for (int i = 0; i < 10; i++) {
        int idx = tid + 256 * i;
        if (idx < 64 * SP / 2) dz[idx] = 0;
      }
    }
    int cg = 16 * wave + lm;
#pragma unroll
    for (int ti = 0; ti < 4; ti++)
#pragma unroll
      for (int r = 0; r < 4; r++) {
        int t = 16 * ti + 4 * quad + r;
        float val;
        if (grp < 8) val = Bt[t] * bf2f(vb[(size_t)(r0 + t) * VDIM_ + grp * 64 + cg]);
        else         val = Bt[t] * Lm[t] * bf2f(kb[(size_t)(r0 + t) * KDIM_ + (grp - 8) * 64 + cg]);
        Ub[t * 64 + cg] = val;
      }
    __syncthreads();

    // forward substitution
#pragma unroll
    for (int j = 0; j < 4; j++) {
      if (j > 0) {
        f32x4 racc = (f32x4){0.f, 0.f, 0.f, 0.f};
        int nk = (j == 3) ? 2 : 1;
        for (int ks = 0; ks < nk; ks++) {
          short8 aa = ld76(&Abf[(size_t)(16 * j + lm) * SP + 8 * quad + 32 * ks]);
          short8 bd = ld76(&DTg[(size_t)(16 * wave + lm) * SP + 8 * quad + 32 * ks]);
          racc = __builtin_amdgcn_mfma_f32_16x16x32_bf16(aa, bd, racc, 0, 0, 0);
        }
#pragma unroll
        for (int r = 0; r < 4; r++)
          Ub[(16 * j + 4 * quad + r) * 64 + 16 * wave + lm] -= racc[r];
        __syncthreads();
      }
      if (wave == 0) {
        int tl = lane & 15, sg = lane >> 4;
        short4v ab4 = *(const short4v*)&Abf[(size_t)(16 * j + tl) * SP + 16 * j + 4 * sg];
        float av[4];
        av[0] = bf2f((bf16)ab4[0]); av[1] = bf2f((bf16)ab4[1]);
        av[2] = bf2f((bf16)ab4[2]); av[3] = bf2f((bf16)ab4[3]);
        float d[16];
#pragma unroll
        for (int t = 0; t < 16; t++) {
          float val = Ub[(16 * j + t) * 64 + lane];
#pragma unroll
          for (int s = 0; s < t; s++) {
            float ats = __shfl(av[s & 3], t + 16 * (s >> 2), 64);
            val -= ats * d[s];
          }
          d[t] = val;
          DTg[(size_t)lane * SP + 16 * j + t] = f2bf(val);
        }
      }
      __syncthreads();
    }

    // store group to Wg / Yg (row-major [t][col])
#pragma unroll
    for (int ti = 0; ti < 4; ti++)
#pragma unroll
      for (int r = 0; r < 4; r++) {
        int t = 16 * ti + 4 * quad + r;
        bf16 val = DTg[(size_t)(16 * wave + lm) * SP + t];
        if (grp < 8) WgC[(size_t)t * 512 + grp * 64 + cg] = val;
        else         YgC[(size_t)t * 256 + (grp - 8) * 64 + cg] = val;
      }
  }
}

// ---------------- delta rule phase 2 (sequential chunks; 256 blocks) ----------------
// Software-pipelined: raw s_barrier (no vmcnt drain), cross-iter register
// prefetch of q/Y fragments, same-iter early issue of P/W fragments, kT chunk
// staged to LDS via global_load_lds in a conflict-free [unit][row] layout.

#define SP2 264
#define SD  72

__global__ __launch_bounds__(256, 1) void delta_p2(const bf16* __restrict__ q,
                                                   const bf16* __restrict__ kT,
                                                   const bf16* __restrict__ Wg,
                                                   const bf16* __restrict__ Yg,
                                                   const bf16* __restrict__ Pg,
                                                   const float* __restrict__ gsc,
                                                   bf16* __restrict__ o) {
  __shared__ bf16 ST[32 * SP2];                  // S^T [v][dk] bf16
  __shared__ bf16 dT[32 * SD];                   // delta^T [v][s]
  __shared__ bf16 dTe[32 * SD];                  // (e*delta)^T [v][s]
  __shared__ float Gc[64];
  __shared__ __align__(16) bf16 Ks[8 * 256 * 8]; // kT chunk, unit (uc*256+row) -> 8 bf16

  int blk = blockIdx.x;
  int vs = blk & 15, bh = blk >> 4;
  int b = bh >> 2, h = bh & 3;
  int tid = threadIdx.x;
  int wave = tid >> 6, lane = tid & 63;
  int lm = lane & 15, quad = lane >> 4;
  int r2 = wave >> 1, ct = wave & 1;
  int v0 = vs * 32;

  const bf16* qb  = q  + (size_t)b * T_ * KDIM_ + h * DK_;
  const bf16* kTb = kT + (size_t)bh * DK_ * T_;
  bf16*       ob  = o  + (size_t)b * T_ * VDIM_ + h * DV_ + v0;

  f32x4 Sacc[8];
#pragma unroll
  for (int i = 0; i < 8; i++) Sacc[i] = (f32x4){0.f, 0.f, 0.f, 0.f};

  // ---- prologue: prefetch chunk-0 q/Y fragments + gsc into registers ----
  float gnext = gsc[(size_t)bh * 32 * 64 + lane];
  short8 qfr[2][8], yfr[2][8];
  {
    const bf16* yc0 = Yg + (size_t)bh * 32 * 64 * 256;
#pragma unroll
    for (int i = 0; i < 2; i++) {
      const bf16* qrow = qb + (size_t)(16 * (2 * r2 + i) + lm) * KDIM_;
      const bf16* yrow = yc0 + (size_t)(16 * (2 * r2 + i) + lm) * 256;
#pragma unroll
      for (int kf = 0; kf < 8; kf++) {
        qfr[i][kf] = *(const short8*)(qrow + 8 * quad + 32 * kf);
        yfr[i][kf] = *(const short8*)(yrow + 8 * quad + 32 * kf);
      }
    }
  }

  for (int c = 0; c < 32; c++) {
    const int r0 = c * 64;
    const size_t cb = (size_t)bh * 32 + c;

    // S1: stage this chunk's kT slab -> Ks (async, consumed at S9)
#pragma unroll
    for (int i = 0; i < 8; i++)
      gload16(kTb + (size_t)tid * T_ + r0 + i * 8, Ks + i * 2048 + wave * 512);
    __builtin_amdgcn_sched_barrier(0);   // pin: Ks issues stay first

    // S2: P fragments (used at S8; their vm wait also covers Ks completion)
    const bf16* pc = Pg + cb * 4096;
    short8 pfr[2][2];
#pragma unroll
    for (int i = 0; i < 2; i++)
#pragma unroll
      for (int kf = 0; kf < 2; kf++)
        pfr[i][kf] = *(const short8*)(pc + (size_t)(16 * (2 * r2 + i) + lm) * 64 + 8 * quad + 32 * kf);

    // S3: W fragments (used at S7)
    const bf16* wcp = Wg + cb * 64 * 512 + v0 + 16 * ct + lm;
    bf16 wfr[2][4];
#pragma unroll
    for (int i = 0; i < 2; i++)
#pragma unroll
      for (int rr = 0; rr < 4; rr++)
        wfr[i][rr] = wcp[(size_t)(16 * (2 * r2 + i) + 4 * quad + rr) * 512];
    __builtin_amdgcn_sched_barrier(0);   // pin: same-chunk loads before prefetch stream

    // S4: stage S^T + Gc; raw barrier (vm prefetches stay in flight)
#pragma unroll
    for (int di = 0; di < 8; di++)
      st4bf(&ST[(size_t)(16 * ct + lm) * SP2 + 16 * (8 * r2 + di) + 4 * quad], Sacc[di]);
    Gc[lane] = gnext;   // all 4 waves write identical values (benign)
    asm volatile("s_waitcnt lgkmcnt(0)" ::: "memory");
    __builtin_amdgcn_s_barrier();

    // S5: Y = Yg@S^T, O = Q@S^T from prefetched regs
    short8 Bs[8];
#pragma unroll
    for (int kf = 0; kf < 8; kf++)
      Bs[kf] = *(const short8*)&ST[(size_t)(16 * ct + lm) * SP2 + 8 * quad + 32 * kf];

    f32x4 Yacc[2], Oacc[2];
#pragma unroll
    for (int i = 0; i < 2; i++) { Yacc[i] = (f32x4){0.f,0.f,0.f,0.f}; Oacc[i] = (f32x4){0.f,0.f,0.f,0.f}; }
#pragma unroll
    for (int i = 0; i < 2; i++)
#pragma unroll
      for (int kf = 0; kf < 8; kf++) {
        Yacc[i] = __builtin_amdgcn_mfma_f32_16x16x32_bf16(yfr[i][kf], Bs[kf], Yacc[i], 0, 0, 0);
        Oacc[i] = __builtin_amdgcn_mfma_f32_16x16x32_bf16(qfr[i][kf], Bs[kf], Oacc[i], 0, 0, 0);
      }

    // S6: prefetch NEXT chunk's q/Y fragments + gsc (cross-iteration)
    __builtin_amdgcn_sched_barrier(0);
    {
      int cn = (c + 1) & 31;          // c=31 wraps to 0: valid addresses, values unused
      size_t cbn = (size_t)bh * 32 + cn;
      int rn = cn * 64;
      gnext = gsc[cbn * 64 + lane];
      const bf16* ycn = Yg + cbn * 64 * 256;
#pragma unroll
      for (int i = 0; i < 2; i++) {
        const bf16* qrow = qb + (size_t)(rn + 16 * (2 * r2 + i) + lm) * KDIM_;
        const bf16* yrow = ycn + (size_t)(16 * (2 * r2 + i) + lm) * 256;
#pragma unroll
        for (int kf = 0; kf < 8; kf++) {
          qfr[i][kf] = *(const short8*)(qrow + 8 * quad + 32 * kf);
          yfr[i][kf] = *(const short8*)(yrow + 8 * quad + 32 * kf);
        }
      }
    }
    __builtin_amdgcn_sched_barrier(0);   // pin: prefetch stream contained here

    // S7: delta = W - Y@S; write dT/dTe; scale O by lam
    float g63 = Gc[63];
#pragma unroll
    for (int i = 0; i < 2; i++) {
      int rt = 2 * r2 + i;
#pragma unroll
      for (int rr = 0; rr < 4; rr++) {
        int row = 16 * rt + 4 * quad + rr;
        float gr  = Gc[row];
        float lam = expf(gr);
        float er  = expf(g63 - gr);
        float dv = bf2f(wfr[i][rr]) - Yacc[i][rr];
        Oacc[i][rr] *= lam;
        dT [(size_t)(16 * ct + lm) * SD + row] = f2bf(dv);
        dTe[(size_t)(16 * ct + lm) * SD + row] = f2bf(dv * er);
      }
    }
    asm volatile("s_waitcnt lgkmcnt(0)" ::: "memory");
    __builtin_amdgcn_s_barrier();

    // S8: O += P@delta, store O
#pragma unroll
    for (int i = 0; i < 2; i++) {
#pragma unroll
      for (int kf = 0; kf < 2; kf++) {
        short8 bd = *(const short8*)&dT[(size_t)(16 * ct + lm) * SD + 8 * quad + 32 * kf];
        Oacc[i] = __builtin_amdgcn_mfma_f32_16x16x32_bf16(pfr[i][kf], bd, Oacc[i], 0, 0, 0);
      }
#pragma unroll
      for (int rr = 0; rr < 4; rr++) {
        int row = 16 * (2 * r2 + i) + 4 * quad + rr;
        ob[(size_t)(r0 + row) * VDIM_ + 16 * ct + lm] = f2bf(Oacc[i][rr]);
      }
    }

    // S9: S update from LDS-staged Ks
    float lend = expf(g63);
    short8 Be[2];
#pragma unroll
    for (int kf = 0; kf < 2; kf++)
      Be[kf] = *(const short8*)&dTe[(size_t)(16 * ct + lm) * SD + 8 * quad + 32 * kf];
#pragma unroll
    for (int di = 0; di < 8; di++) {
      int D = 8 * r2 + di;
      f32x4 s = Sacc[di];
      s[0] *= lend; s[1] *= lend; s[2] *= lend; s[3] *= lend;
#pragma unroll
      for (int kf = 0; kf < 2; kf++) {
        short8 ka = *(const short8*)&Ks[((size_t)(quad + 4 * kf) * 256 + 16 * D + lm) * 8];
        s = __builtin_amdgcn_mfma_f32_16x16x32_bf16(ka, Be[kf], s, 0, 0, 0);
      }
      Sacc[di] = s;
    }
    asm volatile("s_waitcnt lgkmcnt(0)" ::: "memory");
    __builtin_amdgcn_s_barrier();      // protect ST/dT/dTe/Ks overwrite next iter
  }
}

// ---------------- gated RMSNorm (in place, bf16) ----------------

__global__ __launch_bounds__(256) void gated_rms_kernel(bf16* __restrict__ o,
                                                        const bf16* __restrict__ gate,
                                                        const float* __restrict__ onw) {
  __shared__ float red[4];
  int blk = blockIdx.x;
  int h = blk & 3;
  int bt = blk >> 2;
  size_t base = (size_t)bt * VDIM_ + h * DV_;
  int tid = threadIdx.x;
  float o1 = bf2f(o[base + tid]), o2 = bf2f(o[base + tid + 256]);
  float ss = block_sum256(o1 * o1 + o2 * o2, red);
  float s = rsqrtf(ss * (1.f / DV_) + 1e-5f);
  float g1 = bf2f(gate[base + tid]), g2 = bf2f(gate[base + tid + 256]);
  o[base + tid]       = f2bf(o1 * s * onw[tid] * siluf_(g1));
  o[base + tid + 256] = f2bf(o2 * s * onw[tid + 256] * siluf_(g2));
}

// ---------------- launch ----------------

extern "C" void kernel_launch(void* const* d_in, const int* in_sizes, int n_in,
                              void* d_out, int out_size, void* d_ws, size_t ws_size,
                              hipStream_t stream) {
  const float* x        = (const float*)d_in[0];
  const float* Wq       = (const float*)d_in[1];
  const float* Wk       = (const float*)d_in[2];
  const float* Wv       = (const float*)d_in[3];
  const float* Wa       = (const float*)d_in[4];
  const float* Wb       = (const float*)d_in[5];
  const float* Wg       = (const float*)d_in[6];
  const float* conv_q_w = (const float*)d_in[7];
  const float* conv_k_w = (const float*)d_in[8];
  const float* conv_v_w = (const float*)d_in[9];
  const float* A_log    = (const float*)d_in[10];
  const float* dt_bias  = (const float*)d_in[11];
  const float* o_norm_w = (const float*)d_in[12];
  const float* Wo       = (const float*)d_in[13];
  const float* ln1_w    = (const float*)d_in[14];
  const float* ln1_b    = (const float*)d_in[15];
  const float* ln2_w    = (const float*)d_in[16];
  const float* ln2_b    = (const float*)d_in[17];
  const float* ffn_w1   = (const float*)d_in[18];
  const float* ffn_b1   = (const float*)d_in[19];
  const float* ffn_w2   = (const float*)d_in[20];
  const float* ffn_b2   = (const float*)d_in[21];

  size_t required = (size_t)218 << 20;
  if (ws_size < required) {
    sentinel_kernel<<<(out_size + 255) / 256, 256, 0, stream>>>((float*)d_out, out_size);
    return;
  }

  char* base = (char*)d_ws;
  float* pre    = (float*)(base);                        // 64MB scratch (proj outs)
  bf16*  normed = (bf16*)(base + ((size_t)64  << 20));   // 16MB
  bf16*  q16    = (bf16*)(base + ((size_t)80  << 20));   // 16MB
  bf16*  k16    = (bf16*)(base + ((size_t)96  << 20));   // 16MB
  bf16*  v16    = (bf16*)(base + ((size_t)112 << 20));   // 32MB
  bf16*  g16    = (bf16*)(base + ((size_t)144 << 20));   // 32MB
  bf16*  o16    = (bf16*)(base + ((size_t)176 << 20));   // 32MB
  bf16*  wslot  = (bf16*)(base + ((size_t)208 << 20));   // 8MB JIT weight slot
  float* gvec   = (float*)(base + ((size_t)216 << 20));  // 128KB
  float* bvec   = gvec + (size_t)BT_ * H_;               // 128KB
  float* gsc    = (float*)(base + ((size_t)217 << 20));  // 128KB
  // delta-phase buffers (pre region + normed region, dead after ab_kernel):
  bf16*  Yg     = (bf16*)(base);                         // 16MB  [0,16)
  bf16*  Wgb    = (bf16*)(base + ((size_t)16 << 20));    // 32MB  [16,48)
  bf16*  Pg     = (bf16*)(base + ((size_t)48 << 20));    // 4MB   [48,52)
  bf16*  kTg    = (bf16*)(base + ((size_t)52 << 20));    // 16MB  [52,68)
  // later reuses:
  float* x2     = (float*)(base);                        // 32MB (after delta)
  bf16*  hb16   = (bf16*)(base + ((size_t)64  << 20));
  bf16*  ffn1   = (bf16*)(base + ((size_t)80  << 20));

  // 1) LN1 -> bf16
  ln_kernel<<<BT_, 256, 0, stream>>>(x, ln1_w, ln1_b, normed);

  // 2) projections + convs
  convT_kernel<<<dim3(KDIM_ / 32, D_ / 32), 256, 0, stream>>>(Wq, wslot, D_, KDIM_);
  gemm_mfma<float><<<dim3(KDIM_ / 128, BT_ / 128), 256, 0, stream>>>(normed, wslot, nullptr, nullptr, pre, KDIM_, D_, 0);
  conv_qk_kernel<<<BT_ * H_, 256, 0, stream>>>(pre, conv_q_w, q16, 0.0625f);

  convT_kernel<<<dim3(KDIM_ / 32, D_ / 32), 256, 0, stream>>>(Wk, wslot, D_, KDIM_);
  gemm_mfma<float><<<dim3(KDIM_ / 128, BT_ / 128), 256, 0, stream>>>(normed, wslot, nullptr, nullptr, pre, KDIM_, D_, 0);
  conv_qk_kernel<<<BT_ * H_, 256, 0, stream>>>(pre, conv_k_w, k16, 1.0f);

  convT_kernel<<<dim3(VDIM_ / 32, D_ / 32), 256, 0, stream>>>(Wv, wslot, D_, VDIM_);
  gemm_mfma<float><<<dim3(VDIM_ / 128, BT_ / 128), 256, 0, stream>>>(normed, wslot, nullptr, nullptr, pre, VDIM_, D_, 0);
  conv_v_kernel<<<(BT_ * VDIM_) / 256, 256, 0, stream>>>(pre, conv_v_w, v16);

  convT_kernel<<<dim3(VDIM_ / 32, D_ / 32), 256, 0, stream>>>(Wg, wslot, D_, VDIM_);
  gemm_mfma<bf16><<<dim3(VDIM_ / 128, BT_ / 128), 256, 0, stream>>>(normed, wslot, nullptr, nullptr, g16, VDIM_, D_, 0);

  ab_kernel<<<BT_, 256, 0, stream>>>(normed, Wa, Wb, A_log, dt_bias, gvec, bvec);

  // 3) delta rule: kT transpose + parallel phase 1 + pipelined sequential phase 2
  kT_kernel<<<dim3(T_ / 32, DK_ / 32, 16), 256, 0, stream>>>(k16, kTg);
  delta_p1<<<512, 256, 0, stream>>>(q16, k16, v16, gvec, bvec, Pg, Wgb, Yg, gsc);
  delta_p2<<<256, 256, 0, stream>>>(q16, kTg, Wgb, Yg, Pg, gsc, o16);

  // 4) gated RMSNorm (in place)
  gated_rms_kernel<<<BT_ * H_, 256, 0, stream>>>(o16, g16, o_norm_w);

  // 5) x2 = x + o @ Wo
  convT_kernel<<<dim3(D_ / 32, VDIM_ / 32), 256, 0, stream>>>(Wo, wslot, VDIM_, D_);
  gemm_mfma<float><<<dim3(D_ / 128, BT_ / 128), 256, 0, stream>>>(o16, wslot, nullptr, x, x2, D_, VDIM_, 4);

  // 6) LN2 -> bf16
  ln_kernel<<<BT_, 256, 0, stream>>>(x2, ln2_w, ln2_b, hb16);

  // 7) FFN
  convT_kernel<<<dim3(FFN_ / 32, D_ / 32), 256, 0, stream>>>(ffn_w1, wslot, D_, FFN_);
  gemm_mfma<bf16><<<dim3(FFN_ / 128, BT_ / 128), 256, 0, stream>>>(hb16, wslot, ffn_b1, nullptr, ffn1, FFN_, D_, 1 | 2);
  convT_kernel<<<dim3(D_ / 32, FFN_ / 32), 256, 0, stream>>>(ffn_w2, wslot, FFN_, D_);
  gemm_mfma<float><<<dim3(D_ / 128, BT_ / 128), 256, 0, stream>>>(ffn1, wslot, ffn_b2, x2, (float*)d_out, D_, FFN_, 1 | 4);
}

// Round 2
// 1187.080 us; speedup vs baseline: 1.1373x; 1.0537x over previous
//
#include <hip/hip_runtime.h>
#include <math.h>

#define B_    4
#define T_    2048
#define D_    1024
#define H_    4
#define DK_   256
#define DV_   512
#define KDIM_ 1024
#define VDIM_ 2048
#define FFN_  4096
#define BT_   8192   // B_*T_

typedef unsigned short bf16;
typedef __attribute__((ext_vector_type(8))) short short8;   // MFMA A/B frag (8 bf16)
typedef __attribute__((ext_vector_type(4))) short short4v;  // 4 bf16
typedef __attribute__((ext_vector_type(4))) float f32x4;    // MFMA C/D frag

// ---------------- helpers ----------------

__device__ __forceinline__ float sigmoidf_(float x) { return 1.f / (1.f + expf(-x)); }
__device__ __forceinline__ float siluf_(float x)    { return x / (1.f + expf(-x)); }
__device__ __forceinline__ float geluf_(float x)    { return 0.5f * x * (1.f + erff(x * 0.70710678118654752f)); }

__device__ __forceinline__ float bf2f(bf16 u) {
  union { unsigned int i; float f; } c; c.i = (unsigned int)u << 16; return c.f;
}
__device__ __forceinline__ bf16 f2bf(float f) {
  union { unsigned int i; float f; } c; c.f = f;
  unsigned int r = c.i + 0x7fffu + ((c.i >> 16) & 1u);   // RNE
  return (bf16)(r >> 16);
}

// async global->LDS, 16B per lane
__device__ __forceinline__ void gload16(const bf16* g, bf16* l) {
  __builtin_amdgcn_global_load_lds((__attribute__((address_space(1))) const void*)g,
                                   (__attribute__((address_space(3))) void*)l, 16, 0, 0);
}

__device__ __forceinline__ void storeC(float* p, float v) { *p = v; }
__device__ __forceinline__ void storeC(bf16* p, float v)  { *p = f2bf(v); }

// load 8 bf16 from an 8B-aligned LDS address as two b64s
__device__ __forceinline__ short8 ld76(const bf16* p) {
  union { short8 v; short4v h[2]; } u;
  u.h[0] = *(const short4v*)p;
  u.h[1] = *(const short4v*)(p + 4);
  return u.v;
}
// pack f32x4 -> 4 bf16, 8B store
__device__ __forceinline__ void st4bf(bf16* p, f32x4 v) {
  short4v o;
  o[0] = (short)f2bf(v[0]); o[1] = (short)f2bf(v[1]);
  o[2] = (short)f2bf(v[2]); o[3] = (short)f2bf(v[3]);
  *(short4v*)p = o;
}

__device__ __forceinline__ float block_sum256(float v, float* red) {
#pragma unroll
  for (int off = 32; off; off >>= 1) v += __shfl_xor(v, off, 64);
  __syncthreads();
  if ((threadIdx.x & 63) == 0) red[threadIdx.x >> 6] = v;
  __syncthreads();
  return red[0] + red[1] + red[2] + red[3];
}

// ---------------- diagnostic sentinel (ws too small) ----------------

__global__ __launch_bounds__(256) void sentinel_kernel(float* out, int n) {
  int i = blockIdx.x * 256 + threadIdx.x;
  if (i < n) out[i] = 12345.0f;
}

// ---------------- LayerNorm -> bf16 ----------------

__global__ __launch_bounds__(256) void ln_kernel(const float* __restrict__ x,
                                                 const float* __restrict__ w,
                                                 const float* __restrict__ b,
                                                 bf16* __restrict__ y) {
  __shared__ float red[4];
  int row = blockIdx.x;
  const float* xr = x + (size_t)row * D_;
  float xv[4];
  float s = 0.f;
#pragma unroll
  for (int i = 0; i < 4; i++) { xv[i] = xr[threadIdx.x + 256 * i]; s += xv[i]; }
  float mean = block_sum256(s, red) * (1.f / D_);
  float s2 = 0.f;
#pragma unroll
  for (int i = 0; i < 4; i++) { float d = xv[i] - mean; s2 += d * d; }
  float var = block_sum256(s2, red) * (1.f / D_);
  float inv = rsqrtf(var + 1e-5f);
  bf16* yr = y + (size_t)row * D_;
#pragma unroll
  for (int i = 0; i < 4; i++) {
    int c = threadIdx.x + 256 * i;
    yr[c] = f2bf((xv[i] - mean) * inv * w[c] + b[c]);
  }
}

// ---------------- weight convert+transpose: fp32 [K][N] -> bf16 [N][K] ----------------

__global__ __launch_bounds__(256) void convT_kernel(const float* __restrict__ src,
                                                    bf16* __restrict__ dst,
                                                    int K, int N) {
  __shared__ float t[32][33];
  int n0 = blockIdx.x * 32, k0 = blockIdx.y * 32;
  int tx = threadIdx.x & 31, ty = threadIdx.x >> 5;
#pragma unroll
  for (int i = 0; i < 4; i++)
    t[ty + i * 8][tx] = src[(size_t)(k0 + ty + i * 8) * N + n0 + tx];
  __syncthreads();
#pragma unroll
  for (int i = 0; i < 4; i++)
    dst[(size_t)(n0 + ty + i * 8) * K + k0 + tx] = f2bf(t[tx][ty + i * 8]);
}

// ---------------- k transpose per head: k16 [b][t][h*DK+dk] -> kT [bh][dk][t] ----------------

__global__ __launch_bounds__(256) void kT_kernel(const bf16* __restrict__ k16,
                                                 bf16* __restrict__ kT) {
  __shared__ bf16 tile[32][34];
  int t0 = blockIdx.x * 32;
  int d0 = blockIdx.y * 32;
  int bh = blockIdx.z;
  int b = bh >> 2, h = bh & 3;
  int tx = threadIdx.x & 31, ty = threadIdx.x >> 5;
#pragma unroll
  for (int i = 0; i < 4; i++)
    tile[ty + 8 * i][tx] = k16[(size_t)(b * T_ + t0 + ty + 8 * i) * KDIM_ + h * DK_ + d0 + tx];
  __syncthreads();
#pragma unroll
  for (int i = 0; i < 4; i++)
    kT[((size_t)bh * DK_ + d0 + ty + 8 * i) * T_ + t0 + tx] = tile[tx][ty + 8 * i];
}

// ---------------- bf16 MFMA GEMM (unchanged) ----------------

template <typename TC>
__global__ __launch_bounds__(256) void gemm_mfma(const bf16* __restrict__ A,
                                                 const bf16* __restrict__ Bt,
                                                 const float* __restrict__ bias,
                                                 const float* __restrict__ res,
                                                 TC* __restrict__ C,
                                                 int N, int K, int flags) {
  __shared__ __align__(16) bf16 As[128 * 32];
  __shared__ __align__(16) bf16 Bs[128 * 32];
  int tid = threadIdx.x;
  int wave = tid >> 6, lane = tid & 63;
  int bm = blockIdx.y * 128, bn = blockIdx.x * 128;
  int wm = (wave >> 1) * 64, wn = (wave & 1) * 64;
  int lm = lane & 15;
  int quad = lane >> 4;

  f32x4 acc[4][4];
#pragma unroll
  for (int i = 0; i < 4; i++)
#pragma unroll
    for (int j = 0; j < 4; j++) acc[i][j] = (f32x4){0.f, 0.f, 0.f, 0.f};

  int srow = wave * 32 + (lane >> 2);
  int scol = (lane & 3) * 8;
  const bf16* ag = A  + (size_t)(bm + srow) * K + scol;
  const bf16* bg = Bt + (size_t)(bn + srow) * K + scol;
  bf16* al = As + wave * 32 * 32;
  bf16* bl = Bs + wave * 32 * 32;
  const size_t gstep = (size_t)16 * K;

  for (int k0 = 0; k0 < K; k0 += 32) {
    gload16(ag + k0,         al);
    gload16(ag + k0 + gstep, al + 16 * 32);
    gload16(bg + k0,         bl);
    gload16(bg + k0 + gstep, bl + 16 * 32);
    __syncthreads();

    short8 af[4], bf[4];
#pragma unroll
    for (int i = 0; i < 4; i++)
      af[i] = *(const short8*)&As[(wm + i * 16 + lm) * 32 + quad * 8];
#pragma unroll
    for (int j = 0; j < 4; j++)
      bf[j] = *(const short8*)&Bs[(wn + j * 16 + lm) * 32 + quad * 8];
#pragma unroll
    for (int i = 0; i < 4; i++)
#pragma unroll
      for (int j = 0; j < 4; j++)
        acc[i][j] = __builtin_amdgcn_mfma_f32_16x16x32_bf16(af[i], bf[j], acc[i][j], 0, 0, 0);
    __syncthreads();
  }

#pragma unroll
  for (int i = 0; i < 4; i++) {
    int row0 = bm + wm + i * 16 + quad * 4;
#pragma unroll
    for (int j = 0; j < 4; j++) {
      int col = bn + wn + j * 16 + lm;
      float badd = (flags & 1) ? bias[col] : 0.f;
#pragma unroll
      for (int r = 0; r < 4; r++) {
        float v = acc[i][j][r] + badd;
        if (flags & 2) v = geluf_(v);
        if (flags & 4) v += res[(size_t)(row0 + r) * N + col];
        storeC(&C[(size_t)(row0 + r) * N + col], v);
      }
    }
  }
}

// ---------------- fused Wa/Wb projections -> g, beta ----------------

__global__ __launch_bounds__(256) void ab_kernel(const bf16* __restrict__ normed,
                                                 const float* __restrict__ Wa,
                                                 const float* __restrict__ Wb,
                                                 const float* __restrict__ A_log,
                                                 const float* __restrict__ dt_bias,
                                                 float* __restrict__ g,
                                                 float* __restrict__ beta) {
  __shared__ float red[4];
  int row = blockIdx.x;
  const bf16* xr = normed + (size_t)row * D_;
  float aacc[4] = {}, bacc[4] = {};
#pragma unroll
  for (int i = 0; i < 4; i++) {
    int d = threadIdx.x + 256 * i;
    float xv = bf2f(xr[d]);
    float4 wa = *(const float4*)&Wa[d * 4];
    float4 wb = *(const float4*)&Wb[d * 4];
    aacc[0] += xv * wa.x; aacc[1] += xv * wa.y; aacc[2] += xv * wa.z; aacc[3] += xv * wa.w;
    bacc[0] += xv * wb.x; bacc[1] += xv * wb.y; bacc[2] += xv * wb.z; bacc[3] += xv * wb.w;
  }
  float sa[4], sb[4];
#pragma unroll
  for (int h = 0; h < 4; h++) {
    sa[h] = block_sum256(aacc[h], red);
    sb[h] = block_sum256(bacc[h], red);
  }
  if (threadIdx.x < 4) {
    int h = threadIdx.x;
    float xa = sa[h] + dt_bias[h];
    float sp = (xa > 20.f) ? xa : log1pf(expf(xa));
    g[row * 4 + h] = -expf(A_log[h]) * sp;
    beta[row * 4 + h] = sigmoidf_(sb[h]);
  }
}

// ---------------- causal conv(4) + SiLU (+ L2 norm for q/k) ----------------

__global__ __launch_bounds__(256) void conv_qk_kernel(const float* __restrict__ pre,
                                                      const float* __restrict__ convw,
                                                      bf16* __restrict__ out,
                                                      float scale) {
  __shared__ float red[4];
  int blk = blockIdx.x;
  int h = blk & 3;
  int bt = blk >> 2;
  int t = bt & (T_ - 1);
  int c = h * DK_ + threadIdx.x;
  float y = 0.f;
#pragma unroll
  for (int i = 0; i < 4; i++) {
    int tt = t + i - 3;
    if (tt >= 0) y += pre[(size_t)(bt + i - 3) * KDIM_ + c] * convw[c * 4 + i];
  }
  y = siluf_(y);
  float ss = block_sum256(y * y, red);
  y *= rsqrtf(ss + 1e-6f) * scale;
  out[(size_t)bt * KDIM_ + c] = f2bf(y);
}

__global__ __launch_bounds__(256) void conv_v_kernel(const float* __restrict__ pre,
                                                     const float* __restrict__ convw,
                                                     bf16* __restrict__ out) {
  int idx = blockIdx.x * 256 + threadIdx.x;
  int c = idx & (VDIM_ - 1);
  int bt = idx >> 11;
  int t = bt & (T_ - 1);
  float y = 0.f;
#pragma unroll
  for (int i = 0; i < 4; i++) {
    int tt = t + i - 3;
    if (tt >= 0) y += pre[(size_t)(bt + i - 3) * VDIM_ + c] * convw[c * 4 + i];
  }
  out[idx] = f2bf(siluf_(y));
}

// ---------------- delta rule phase 1 (parallel over bh x chunk) ----------------

#define SP 76

__global__ __launch_bounds__(256, 2) void delta_p1(const bf16* __restrict__ q,
                                                   const bf16* __restrict__ k,
                                                   const bf16* __restrict__ v,
                                                   const float* __restrict__ g,
                                                   const float* __restrict__ beta,
                                                   bf16* __restrict__ Pg,
                                                   bf16* __restrict__ Wg,
                                                   bf16* __restrict__ Yg,
                                                   float* __restrict__ gsc) {
  __shared__ bf16 Abf[64 * SP];
  __shared__ bf16 DTg[64 * SP];
  __shared__ float Ub[64 * 64];
  __shared__ float Gc[64], Lm[64], Bt[64];

  int blk = blockIdx.x;
  int c = blk & 31, bh = blk >> 5;
  int b = bh >> 2, h = bh & 3;
  int tid = threadIdx.x;
  int wave = tid >> 6, lane = tid & 63;
  int lm = lane & 15, quad = lane >> 4;
  int r0 = c * 64;

  const bf16* kb = k + (size_t)b * T_ * KDIM_ + h * DK_;
  const bf16* qb = q + (size_t)b * T_ * KDIM_ + h * DK_;
  const bf16* vb = v + (size_t)b * T_ * VDIM_ + h * DV_;
  const float* gbp = g    + (size_t)b * T_ * H_ + h;
  const float* bbp = beta + (size_t)b * T_ * H_ + h;
  size_t cb = (size_t)bh * 32 + c;
  bf16* PgC = Pg + cb * 4096;
  bf16* WgC = Wg + cb * 64 * 512;
  bf16* YgC = Yg + cb * 64 * 256;

  // (a) cumsum of g -> Gc, Lam, beta
  if (wave == 0) {
    float gv = gbp[(size_t)(r0 + lane) * H_];
    float bv = bbp[(size_t)(r0 + lane) * H_];
#pragma unroll
    for (int d = 1; d < 64; d <<= 1) {
      float nn = __shfl_up(gv, (unsigned)d, 64);
      if (lane >= d) gv += nn;
    }
    Gc[lane] = gv; Lm[lane] = expf(gv); Bt[lane] = bv;
    gsc[cb * 64 + lane] = gv;
  }
  __syncthreads();

  // (b,c) KK^T -> Abf, QK^T -> Pg
  {
    f32x4 akk[4], aqk[4];
#pragma unroll
    for (int j = 0; j < 4; j++) { akk[j] = (f32x4){0.f,0.f,0.f,0.f}; aqk[j] = (f32x4){0.f,0.f,0.f,0.f}; }
    const bf16* krow = kb + (size_t)(r0 + 16 * wave + lm) * KDIM_;
    const bf16* qrow = qb + (size_t)(r0 + 16 * wave + lm) * KDIM_;
#pragma unroll
    for (int ks = 0; ks < 8; ks++) {
      short8 ak = *(const short8*)(krow + 8 * quad + 32 * ks);
      short8 aq = *(const short8*)(qrow + 8 * quad + 32 * ks);
#pragma unroll
      for (int j = 0; j < 4; j++) {
        short8 bk = *(const short8*)(kb + (size_t)(r0 + 16 * j + lm) * KDIM_ + 8 * quad + 32 * ks);
        akk[j] = __builtin_amdgcn_mfma_f32_16x16x32_bf16(ak, bk, akk[j], 0, 0, 0);
        aqk[j] = __builtin_amdgcn_mfma_f32_16x16x32_bf16(aq, bk, aqk[j], 0, 0, 0);
      }
    }
    float gi[4], bi[4];
#pragma unroll
    for (int r = 0; r < 4; r++) {
      int i = 16 * wave + 4 * quad + r;
      gi[r] = Gc[i]; bi[r] = Bt[i];
    }
#pragma unroll
    for (int j = 0; j < 4; j++) {
      int s = 16 * j + lm;
      float gs = Gc[s];
#pragma unroll
      for (int r = 0; r < 4; r++) {
        int i = 16 * wave + 4 * quad + r;
        float dec = expf(gi[r] - gs);
        Abf[(size_t)i * SP + s] = f2bf((s < i)  ? bi[r] * dec * akk[j][r] : 0.f);
        PgC[(size_t)i * 64 + s] = f2bf((s <= i) ? dec * aqk[j][r]        : 0.f);
      }
    }
  }

  // 12 column groups of 64: grp 0..7 -> W (RHS beta*V), grp 8..11 -> Y (RHS beta*Lam*K)
  for (int grp = 0; grp < 12; grp++) {
    __syncthreads();        // Abf ready (grp0) / prev DTg stores done
    {
      int* dz = (int*)DTg;
#pragma unroll
      for (int i = 0; i < 10; i++) {
        int idx = tid + 256 * i;
        if (idx < 64 * SP / 2) dz[idx] = 0;
      }
    }
    int cg = 16 * wave + lm;
#pragma unroll
    for (int ti = 0; ti < 4; ti++)
#pragma unroll
      for (int r = 0; r < 4; r++) {
        int t = 16 * ti + 4 * quad + r;
        float val;
        if (grp < 8) val = Bt[t] * bf2f(vb[(size_t)(r0 + t) * VDIM_ + grp * 64 + cg]);
        else         val = Bt[t] * Lm[t] * bf2f(kb[(size_t)(r0 + t) * KDIM_ + (grp - 8) * 64 + cg]);
        Ub[t * 64 + cg] = val;
      }
    __syncthreads();

    // forward substitution
#pragma unroll
    for (int j = 0; j < 4; j++) {
      if (j > 0) {
        f32x4 racc = (f32x4){0.f, 0.f, 0.f, 0.f};
        int nk = (j == 3) ? 2 : 1;
        for (int ks = 0; ks < nk; ks++) {
          short8 aa = ld76(&Abf[(size_t)(16 * j + lm) * SP + 8 * quad + 32 * ks]);
          short8 bd = ld76(&DTg[(size_t)(16 * wave + lm) * SP + 8 * quad + 32 * ks]);
          racc = __builtin_amdgcn_mfma_f32_16x16x32_bf16(aa, bd, racc, 0, 0, 0);
        }
#pragma unroll
        for (int r = 0; r < 4; r++)
          Ub[(16 * j + 4 * quad + r) * 64 + 16 * wave + lm] -= racc[r];
        __syncthreads();
      }
      if (wave == 0) {
        int tl = lane & 15, sg = lane >> 4;
        short4v ab4 = *(const short4v*)&Abf[(size_t)(16 * j + tl) * SP + 16 * j + 4 * sg];
        float av[4];
        av[0] = bf2f((bf16)ab4[0]); av[1] = bf2f((bf16)ab4[1]);
        av[2] = bf2f((bf16)ab4[2]); av[3] = bf2f((bf16)ab4[3]);
        float d[16];
#pragma unroll
        for (int t = 0; t < 16; t++) {
          float val = Ub[(16 * j + t) * 64 + lane];
#pragma unroll
          for (int s = 0; s < t; s++) {
            float ats = __shfl(av[s & 3], t + 16 * (s >> 2), 64);
            val -= ats * d[s];
          }
          d[t] = val;
          DTg[(size_t)lane * SP + 16 * j + t] = f2bf(val);
        }
      }
      __syncthreads();
    }

    // store group to Wg / Yg (row-major [t][col])
#pragma unroll
    for (int ti = 0; ti < 4; ti++)
#pragma unroll
      for (int r = 0; r < 4; r++) {
        int t = 16 * ti + 4 * quad + r;
        bf16 val = DTg[(size_t)(16 * wave + lm) * SP + t];
        if (grp < 8) WgC[(size_t)t * 512 + grp * 64 + cg] = val;
        else         YgC[(size_t)t * 256 + (grp - 8) * 64 + cg] = val;
      }
  }
}

// ---------------- delta rule phase 2 (sequential chunks; 256 blocks) ----------------
// R2: one row-tile per wave (unique q/Y/P frags per wave -> no duplicate L2
// traffic), W staged via global_load_lds (coalesced; was 64-way-divergent
// scalar loads), packed b64 dT/dTe writes, __expf, S-update before O-epilogue.
// Completion of Ks/Ws gload_lds is forced by tying the later-issued pfr regs
// into a volatile asm at S7 (compiler computes the vmcnt; no manual count).

#define SP2 264
#define SD  72

__global__ __launch_bounds__(256, 1) void delta_p2(const bf16* __restrict__ q,
                                                   const bf16* __restrict__ kT,
                                                   const bf16* __restrict__ Wg,
                                                   const bf16* __restrict__ Yg,
                                                   const bf16* __restrict__ Pg,
                                                   const float* __restrict__ gsc,
                                                   bf16* __restrict__ o) {
  __shared__ __align__(16) bf16 ST[32 * SP2];    // S^T [v][dk] bf16
  __shared__ __align__(16) bf16 dT[32 * SD];     // delta^T [v][t]
  __shared__ __align__(16) bf16 dTe[32 * SD];    // (e*delta)^T [v][t]
  __shared__ float Gc[64];
  __shared__ __align__(16) bf16 Ks[8 * 256 * 8]; // kT chunk, unit (i*256+dk) -> 8 bf16
  __shared__ __align__(16) bf16 Ws[64 * 32];     // W chunk slab [t][32 v-cols], linear

  int blk = blockIdx.x;
  int vs = blk & 15, bh = blk >> 4;
  int b = bh >> 2, h = bh & 3;
  int tid = threadIdx.x;
  int wave = tid >> 6, lane = tid & 63;
  int lm = lane & 15, quad = lane >> 4;
  int rt = wave;                       // row-tile (t rows 16rt..16rt+15)
  int v0 = vs * 32;

  const bf16* qb  = q  + (size_t)b * T_ * KDIM_ + h * DK_;
  const bf16* kTb = kT + (size_t)bh * DK_ * T_;
  bf16*       ob  = o  + (size_t)b * T_ * VDIM_ + h * DV_ + v0;

  f32x4 Sacc[4][2];                    // dk-tile (4*wave+dd) x v-col-tile cc
#pragma unroll
  for (int dd = 0; dd < 4; dd++)
#pragma unroll
    for (int cc = 0; cc < 2; cc++) Sacc[dd][cc] = (f32x4){0.f, 0.f, 0.f, 0.f};

  // ---- prologue: prefetch chunk-0 q/Y fragments + gsc ----
  float gnext = gsc[(size_t)bh * 2048 + lane];
  short8 qfr[8], yfr[8];
  {
    const bf16* qrow = qb + (size_t)(16 * rt + lm) * KDIM_;
    const bf16* yrow = Yg + (size_t)bh * 32 * 16384 + (size_t)(16 * rt + lm) * 256;
#pragma unroll
    for (int kf = 0; kf < 8; kf++) {
      qfr[kf] = *(const short8*)(qrow + 8 * quad + 32 * kf);
      yfr[kf] = *(const short8*)(yrow + 8 * quad + 32 * kf);
    }
  }

  for (int c = 0; c < 32; c++) {
    const int r0 = c * 64;
    const size_t cb = (size_t)bh * 32 + c;

    // S1: stage kT slab + W slab -> LDS (async, consumed at S9 / S7)
#pragma unroll
    for (int i = 0; i < 8; i++)
      gload16(kTb + (size_t)tid * T_ + r0 + i * 8, Ks + i * 2048 + wave * 512);
    gload16(Wg + cb * 32768 + (size_t)(tid >> 2) * 512 + v0 + (tid & 3) * 8, Ws + tid * 8);
    __builtin_amdgcn_sched_barrier(0);

    // S2: P fragments (issued AFTER Ks/Ws -> their wait covers both)
    const bf16* pc = Pg + cb * 4096 + (size_t)(16 * rt + lm) * 64 + 8 * quad;
    short8 pfr[2];
    pfr[0] = *(const short8*)(pc);
    pfr[1] = *(const short8*)(pc + 32);
    __builtin_amdgcn_sched_barrier(0);

    // S4: stage S^T + Gc; raw barrier (vm loads stay in flight)
#pragma unroll
    for (int dd = 0; dd < 4; dd++)
#pragma unroll
      for (int cc = 0; cc < 2; cc++)
        st4bf(&ST[(size_t)(16 * cc + lm) * SP2 + 16 * (4 * wave + dd) + 4 * quad], Sacc[dd][cc]);
    Gc[lane] = gnext;   // all 4 waves write identical values (benign)
    asm volatile("s_waitcnt lgkmcnt(0)" ::: "memory");
    __builtin_amdgcn_s_barrier();

    // S5: Y = Yg@S^T, O = Q@S^T (A-frags unique per wave)
    f32x4 Yacc[2], Oacc[2];
#pragma unroll
    for (int cc = 0; cc < 2; cc++) { Yacc[cc] = (f32x4){0.f,0.f,0.f,0.f}; Oacc[cc] = (f32x4){0.f,0.f,0.f,0.f}; }
#pragma unroll
    for (int cc = 0; cc < 2; cc++) {
      short8 Bs[8];
#pragma unroll
      for (int kf = 0; kf < 8; kf++)
        Bs[kf] = *(const short8*)&ST[(size_t)(16 * cc + lm) * SP2 + 8 * quad + 32 * kf];
#pragma unroll
      for (int kf = 0; kf < 8; kf++) {
        Yacc[cc] = __builtin_amdgcn_mfma_f32_16x16x32_bf16(yfr[kf], Bs[kf], Yacc[cc], 0, 0, 0);
        Oacc[cc] = __builtin_amdgcn_mfma_f32_16x16x32_bf16(qfr[kf], Bs[kf], Oacc[cc], 0, 0, 0);
      }
    }
    __builtin_amdgcn_sched_barrier(0);

    // S6: prefetch NEXT chunk's q/Y fragments + gsc
    {
      int cn = (c + 1) & 31;          // c=31 wraps: valid addresses, unused
      size_t cbn = (size_t)bh * 32 + cn;
      gnext = gsc[cbn * 64 + lane];
      const bf16* qrow = qb + (size_t)(cn * 64 + 16 * rt + lm) * KDIM_;
      const bf16* yrow = Yg + cbn * 16384 + (size_t)(16 * rt + lm) * 256;
#pragma unroll
      for (int kf = 0; kf < 8; kf++) {
        qfr[kf] = *(const short8*)(qrow + 8 * quad + 32 * kf);
        yfr[kf] = *(const short8*)(yrow + 8 * quad + 32 * kf);
      }
    }
    __builtin_amdgcn_sched_barrier(0);

    // S7: wait pfr (covers Ks/Ws); delta = W - Y@S; dT/dTe; scale O by lam
    asm volatile("" : : "v"(*(const int*)&pfr[0]), "v"(*(const int*)&pfr[1]) : "memory");
    __builtin_amdgcn_sched_barrier(0);
    float g63 = Gc[63];
    float lamv[4], erv[4];
#pragma unroll
    for (int rr = 0; rr < 4; rr++) {
      float gr = Gc[16 * rt + 4 * quad + rr];
      lamv[rr] = __expf(gr);
      erv[rr]  = __expf(g63 - gr);
    }
#pragma unroll
    for (int cc = 0; cc < 2; cc++) {
      short4v dpack, depack;
#pragma unroll
      for (int rr = 0; rr < 4; rr++) {
        int row = 16 * rt + 4 * quad + rr;
        float dv = bf2f(Ws[row * 32 + 16 * cc + lm]) - Yacc[cc][rr];
        Oacc[cc][rr] *= lamv[rr];
        dpack[rr]  = (short)f2bf(dv);
        depack[rr] = (short)f2bf(dv * erv[rr]);
      }
      *(short4v*)&dT [(size_t)(16 * cc + lm) * SD + 16 * rt + 4 * quad] = dpack;
      *(short4v*)&dTe[(size_t)(16 * cc + lm) * SD + 16 * rt + 4 * quad] = depack;
    }
    asm volatile("s_waitcnt lgkmcnt(0)" ::: "memory");
    __builtin_amdgcn_s_barrier();

    // S9 first (critical path): S <- lend*S + K^T @ (e*delta)
    float lend = __expf(g63);
    short8 Be[2][2];
#pragma unroll
    for (int cc = 0; cc < 2; cc++)
#pragma unroll
      for (int kf = 0; kf < 2; kf++)
        Be[cc][kf] = ld76(&dTe[(size_t)(16 * cc + lm) * SD + 8 * quad + 32 * kf]);
#pragma unroll
    for (int dd = 0; dd < 4; dd++) {
      int Dt = 4 * wave + dd;
#pragma unroll
      for (int cc = 0; cc < 2; cc++) {
        f32x4 s = Sacc[dd][cc];
        s[0] *= lend; s[1] *= lend; s[2] *= lend; s[3] *= lend;
#pragma unroll
        for (int kf = 0; kf < 2; kf++) {
          short8 ka = *(const short8*)&Ks[((size_t)(quad + 4 * kf) * 256 + 16 * Dt + lm) * 8];
          s = __builtin_amdgcn_mfma_f32_16x16x32_bf16(ka, Be[cc][kf], s, 0, 0, 0);
        }
        Sacc[dd][cc] = s;
      }
    }

    // S8: O += P@delta, store O
#pragma unroll
    for (int cc = 0; cc < 2; cc++) {
#pragma unroll
      for (int kf = 0; kf < 2; kf++) {
        short8 bd = ld76(&dT[(size_t)(16 * cc + lm) * SD + 8 * quad + 32 * kf]);
        Oacc[cc] = __builtin_amdgcn_mfma_f32_16x16x32_bf16(pfr[kf], bd, Oacc[cc], 0, 0, 0);
      }
#pragma unroll
      for (int rr = 0; rr < 4; rr++) {
        int row = 16 * rt + 4 * quad + rr;
        ob[(size_t)(r0 + row) * VDIM_ + 16 * cc + lm] = f2bf(Oacc[cc][rr]);
      }
    }
    asm volatile("s_waitcnt lgkmcnt(0)" ::: "memory");
    __builtin_amdgcn_s_barrier();      // protect ST/dT/dTe/Ks/Ws overwrite next iter
  }
}

// ---------------- gated RMSNorm (in place, bf16) ----------------

__global__ __launch_bounds__(256) void gated_rms_kernel(bf16* __restrict__ o,
                                                        const bf16* __restrict__ gate,
                                                        const float* __restrict__ onw) {
  __shared__ float red[4];
  int blk = blockIdx.x;
  int h = blk & 3;
  int bt = blk >> 2;
  size_t base = (size_t)bt * VDIM_ + h * DV_;
  int tid = threadIdx.x;
  float o1 = bf2f(o[base + tid]), o2 = bf2f(o[base + tid + 256]);
  float ss = block_sum256(o1 * o1 + o2 * o2, red);
  float s = rsqrtf(ss * (1.f / DV_) + 1e-5f);
  float g1 = bf2f(gate[base + tid]), g2 = bf2f(gate[base + tid + 256]);
  o[base + tid]       = f2bf(o1 * s * onw[tid] * siluf_(g1));
  o[base + tid + 256] = f2bf(o2 * s * onw[tid + 256] * siluf_(g2));
}

// ---------------- launch ----------------

extern "C" void kernel_launch(void* const* d_in, const int* in_sizes, int n_in,
                              void* d_out, int out_size, void* d_ws, size_t ws_size,
                              hipStream_t stream) {
  const float* x        = (const float*)d_in[0];
  const float* Wq       = (const float*)d_in[1];
  const float* Wk       = (const float*)d_in[2];
  const float* Wv       = (const float*)d_in[3];
  const float* Wa       = (const float*)d_in[4];
  const float* Wb       = (const float*)d_in[5];
  const float* Wg       = (const float*)d_in[6];
  const float* conv_q_w = (const float*)d_in[7];
  const float* conv_k_w = (const float*)d_in[8];
  const float* conv_v_w = (const float*)d_in[9];
  const float* A_log    = (const float*)d_in[10];
  const float* dt_bias  = (const float*)d_in[11];
  const float* o_norm_w = (const float*)d_in[12];
  const float* Wo       = (const float*)d_in[13];
  const float* ln1_w    = (const float*)d_in[14];
  const float* ln1_b    = (const float*)d_in[15];
  const float* ln2_w    = (const float*)d_in[16];
  const float* ln2_b    = (const float*)d_in[17];
  const float* ffn_w1   = (const float*)d_in[18];
  const float* ffn_b1   = (const float*)d_in[19];
  const float* ffn_w2   = (const float*)d_in[20];
  const float* ffn_b2   = (const float*)d_in[21];

  size_t required = (size_t)218 << 20;
  if (ws_size < required) {
    sentinel_kernel<<<(out_size + 255) / 256, 256, 0, stream>>>((float*)d_out, out_size);
    return;
  }

  char* base = (char*)d_ws;
  float* pre    = (float*)(base);                        // 64MB scratch (proj outs)
  bf16*  normed = (bf16*)(base + ((size_t)64  << 20));   // 16MB
  bf16*  q16    = (bf16*)(base + ((size_t)80  << 20));   // 16MB
  bf16*  k16    = (bf16*)(base + ((size_t)96  << 20));   // 16MB
  bf16*  v16    = (bf16*)(base + ((size_t)112 << 20));   // 32MB
  bf16*  g16    = (bf16*)(base + ((size_t)144 << 20));   // 32MB
  bf16*  o16    = (bf16*)(base + ((size_t)176 << 20));   // 32MB
  bf16*  wslot  = (bf16*)(base + ((size_t)208 << 20));   // 8MB JIT weight slot
  float* gvec   = (float*)(base + ((size_t)216 << 20));  // 128KB
  float* bvec   = gvec + (size_t)BT_ * H_;               // 128KB
  float* gsc    = (float*)(base + ((size_t)217 << 20));  // 128KB
  // delta-phase buffers (pre region + normed region, dead after ab_kernel):
  bf16*  Yg     = (bf16*)(base);                         // 16MB  [0,16)
  bf16*  Wgb    = (bf16*)(base + ((size_t)16 << 20));    // 32MB  [16,48)
  bf16*  Pg     = (bf16*)(base + ((size_t)48 << 20));    // 4MB   [48,52)
  bf16*  kTg    = (bf16*)(base + ((size_t)52 << 20));    // 16MB  [52,68)
  // later reuses:
  float* x2     = (float*)(base);                        // 32MB (after delta)
  bf16*  hb16   = (bf16*)(base + ((size_t)64  << 20));
  bf16*  ffn1   = (bf16*)(base + ((size_t)80  << 20));

  // 1) LN1 -> bf16
  ln_kernel<<<BT_, 256, 0, stream>>>(x, ln1_w, ln1_b, normed);

  // 2) projections + convs
  convT_kernel<<<dim3(KDIM_ / 32, D_ / 32), 256, 0, stream>>>(Wq, wslot, D_, KDIM_);
  gemm_mfma<float><<<dim3(KDIM_ / 128, BT_ / 128), 256, 0, stream>>>(normed, wslot, nullptr, nullptr, pre, KDIM_, D_, 0);
  conv_qk_kernel<<<BT_ * H_, 256, 0, stream>>>(pre, conv_q_w, q16, 0.0625f);

  convT_kernel<<<dim3(KDIM_ / 32, D_ / 32), 256, 0, stream>>>(Wk, wslot, D_, KDIM_);
  gemm_mfma<float><<<dim3(KDIM_ / 128, BT_ / 128), 256, 0, stream>>>(normed, wslot, nullptr, nullptr, pre, KDIM_, D_, 0);
  conv_qk_kernel<<<BT_ * H_, 256, 0, stream>>>(pre, conv_k_w, k16, 1.0f);

  convT_kernel<<<dim3(VDIM_ / 32, D_ / 32), 256, 0, stream>>>(Wv, wslot, D_, VDIM_);
  gemm_mfma<float><<<dim3(VDIM_ / 128, BT_ / 128), 256, 0, stream>>>(normed, wslot, nullptr, nullptr, pre, VDIM_, D_, 0);
  conv_v_kernel<<<(BT_ * VDIM_) / 256, 256, 0, stream>>>(pre, conv_v_w, v16);

  convT_kernel<<<dim3(VDIM_ / 32, D_ / 32), 256, 0, stream>>>(Wg, wslot, D_, VDIM_);
  gemm_mfma<bf16><<<dim3(VDIM_ / 128, BT_ / 128), 256, 0, stream>>>(normed, wslot, nullptr, nullptr, g16, VDIM_, D_, 0);

  ab_kernel<<<BT_, 256, 0, stream>>>(normed, Wa, Wb, A_log, dt_bias, gvec, bvec);

  // 3) delta rule: kT transpose + parallel phase 1 + pipelined sequential phase 2
  kT_kernel<<<dim3(T_ / 32, DK_ / 32, 16), 256, 0, stream>>>(k16, kTg);
  delta_p1<<<512, 256, 0, stream>>>(q16, k16, v16, gvec, bvec, Pg, Wgb, Yg, gsc);
  delta_p2<<<256, 256, 0, stream>>>(q16, kTg, Wgb, Yg, Pg, gsc, o16);

  // 4) gated RMSNorm (in place)
  gated_rms_kernel<<<BT_ * H_, 256, 0, stream>>>(o16, g16, o_norm_w);

  // 5) x2 = x + o @ Wo
  convT_kernel<<<dim3(D_ / 32, VDIM_ / 32), 256, 0, stream>>>(Wo, wslot, VDIM_, D_);
  gemm_mfma<float><<<dim3(D_ / 128, BT_ / 128), 256, 0, stream>>>(o16, wslot, nullptr, x, x2, D_, VDIM_, 4);

  // 6) LN2 -> bf16
  ln_kernel<<<BT_, 256, 0, stream>>>(x2, ln2_w, ln2_b, hb16);

  // 7) FFN
  convT_kernel<<<dim3(FFN_ / 32, D_ / 32), 256, 0, stream>>>(ffn_w1, wslot, D_, FFN_);
  gemm_mfma<bf16><<<dim3(FFN_ / 128, BT_ / 128), 256, 0, stream>>>(hb16, wslot, ffn_b1, nullptr, ffn1, FFN_, D_, 1 | 2);
  convT_kernel<<<dim3(D_ / 32, FFN_ / 32), 256, 0, stream>>>(ffn_w2, wslot, FFN_, D_);
  gemm_mfma<float><<<dim3(D_ / 128, BT_ / 128), 256, 0, stream>>>(ffn1, wslot, ffn_b2, x2, (float*)d_out, D_, FFN_, 1 | 4);
}